// Round 5
// baseline (242.986 us; speedup 1.0000x reference)
//
#include <hip/hip_runtime.h>
#include <math.h>

__device__ __forceinline__ float gelu_f(float x) {
    return 0.5f * x * (1.0f + erff(x * 0.7071067811865476f));
}

// ---------------------------------------------------------------------------
// K0: precompute cc[k] = sum_c cb[k][c]^2   (512 codes, 32 ch)
// ---------------------------------------------------------------------------
__global__ __launch_bounds__(256) void k_prep(const float* __restrict__ cb,
                                              float* __restrict__ ccp) {
    const int k = blockIdx.x * 256 + threadIdx.x;
    if (k < 512) {
        const float* row = cb + k * 32;
        float s = 0.f;
#pragma unroll
        for (int c = 0; c < 32; ++c) s += row[c] * row[c];
        ccp[k] = s;
    }
}

// ---------------------------------------------------------------------------
// K1: conv1 (1->16, 3x3, SAME) + maxpool2 + gelu
// x[128,1,128,128] -> h1[128,16,64,64]
// LDS de-interleaved into even/odd column planes (stride 38: E at 0..16,
// O at 19..35) so pat reads are b32 with <=3-way banks instead of 4-way b64.
// ---------------------------------------------------------------------------
__global__ __launch_bounds__(256) void k_conv1(const float* __restrict__ x,
                                               const float* __restrict__ w1,
                                               const float* __restrict__ b1,
                                               float* __restrict__ h1) {
    __shared__ float xs[34 * 38];
    const int blk = blockIdx.x;
    const int b = blk >> 4;
    const int tile = blk & 15;
    const int ti = (tile >> 2) << 4, tj = (tile & 3) << 4;
    const int t = threadIdx.x;
    const float* xb = x + b * 16384;
    for (int i = t; i < 34 * 34; i += 256) {
        const int r = i / 34, c = i % 34;
        const int gr = 2 * ti - 1 + r, gc = 2 * tj - 1 + c;
        const float v = ((unsigned)gr < 128u && (unsigned)gc < 128u) ? xb[gr * 128 + gc] : 0.f;
        xs[r * 38 + (c & 1) * 19 + (c >> 1)] = v;
    }
    __syncthreads();
    const int jj = t & 15, ii = t >> 4;
    float pat[4][4];
#pragma unroll
    for (int r = 0; r < 4; r++) {
        const int row = (2 * ii + r) * 38;
        pat[r][0] = xs[row + jj];
        pat[r][1] = xs[row + 19 + jj];
        pat[r][2] = xs[row + jj + 1];
        pat[r][3] = xs[row + 20 + jj];
    }
    const int obase = b * 65536 + (ti + ii) * 64 + (tj + jj);
#pragma unroll 2
    for (int co = 0; co < 16; co++) {
        const float* wr = w1 + co * 9;
        float w[9];
#pragma unroll
        for (int k = 0; k < 9; k++) w[k] = wr[k];
        float s00 = 0.f, s01 = 0.f, s10 = 0.f, s11 = 0.f;
#pragma unroll
        for (int ty = 0; ty < 3; ty++)
#pragma unroll
            for (int tx = 0; tx < 3; tx++) {
                const float wv = w[ty * 3 + tx];
                s00 += wv * pat[ty][tx];
                s01 += wv * pat[ty][tx + 1];
                s10 += wv * pat[ty + 1][tx];
                s11 += wv * pat[ty + 1][tx + 1];
            }
        const float m = fmaxf(fmaxf(s00, s01), fmaxf(s10, s11)) + b1[co];
        h1[obase + co * 4096] = gelu_f(m);
    }
}

// ---------------------------------------------------------------------------
// K2: conv2 (16->32, 3x3, SAME) + maxpool2
// h1[128,16,64,64] -> h[128,32,32,32]
// Wave = co-octet (SGPR weights). Lane = 8x8 pooled tile pos.
// LDS plane-split per row (stride 20: E cols at 0..8, O at 10..18); pat via
// 4 b32 reads -> banks 8*(irow&3)+j = bijection on 32 banks, 2-way (free).
// ---------------------------------------------------------------------------
__global__ __launch_bounds__(256) void k_conv2(const float* __restrict__ h1,
                                               const float* __restrict__ w2,
                                               const float* __restrict__ b2,
                                               float* __restrict__ h) {
    __shared__ float hs[16 * 360];
    const int blk = blockIdx.x;
    const int b = blk >> 4;
    const int tile = blk & 15;
    const int ti = (tile >> 2) << 3, tj = (tile & 3) << 3;
    const int t = threadIdx.x;
    const float* h1b = h1 + b * 65536;
    for (int i = t; i < 16 * 324; i += 256) {
        const int ci = i / 324, rc = i % 324, r = rc / 18, c = rc % 18;
        const int gr = 2 * ti - 1 + r, gc = 2 * tj - 1 + c;
        const float v = ((unsigned)gr < 64u && (unsigned)gc < 64u) ? h1b[ci * 4096 + gr * 64 + gc] : 0.f;
        hs[ci * 360 + r * 20 + (c & 1) * 10 + (c >> 1)] = v;
    }
    __syncthreads();
    const int co0 = __builtin_amdgcn_readfirstlane((t >> 6) << 3);
    const int lane = t & 63;
    const int irow = lane >> 3, j = lane & 7;
    float acc[8][4];
#pragma unroll
    for (int q = 0; q < 8; q++) { acc[q][0] = 0.f; acc[q][1] = 0.f; acc[q][2] = 0.f; acc[q][3] = 0.f; }
    const float* wbase = w2 + co0 * 144;
#pragma unroll 4
    for (int ci = 0; ci < 16; ci++) {
        float pat[4][4];
#pragma unroll
        for (int r = 0; r < 4; r++) {
            const int row = ci * 360 + (2 * irow + r) * 20;
            pat[r][0] = hs[row + j];
            pat[r][1] = hs[row + 10 + j];
            pat[r][2] = hs[row + j + 1];
            pat[r][3] = hs[row + 11 + j];
        }
#pragma unroll
        for (int q = 0; q < 8; q++) {
            const float* wr = wbase + q * 144 + ci * 9;
            float w[9];
#pragma unroll
            for (int k = 0; k < 9; k++) w[k] = wr[k];
#pragma unroll
            for (int ty = 0; ty < 3; ty++)
#pragma unroll
                for (int tx = 0; tx < 3; tx++) {
                    const float wv = w[ty * 3 + tx];
                    acc[q][0] += wv * pat[ty][tx];
                    acc[q][1] += wv * pat[ty][tx + 1];
                    acc[q][2] += wv * pat[ty + 1][tx];
                    acc[q][3] += wv * pat[ty + 1][tx + 1];
                }
        }
    }
    float* hb = h + (b * 32 + co0) * 1024 + (ti + irow) * 32 + tj + j;
#pragma unroll
    for (int q = 0; q < 8; q++) {
        hb[q * 1024] = fmaxf(fmaxf(acc[q][0], acc[q][1]), fmaxf(acc[q][2], acc[q][3])) + b2[co0 + q];
    }
}

// ---------------------------------------------------------------------------
// K3a: VQ partial argmin (unchanged from passing R3/R4).
// ---------------------------------------------------------------------------
__global__ __launch_bounds__(256) void k_vq_part(const float* __restrict__ h,
                                                 const float* __restrict__ cb,
                                                 const float* __restrict__ ccp,
                                                 float2* __restrict__ part) {
    const int blk = blockIdx.x;
    const int nchunk = blk >> 2, ks = blk & 3;
    const int t = threadIdx.x;
    const int n = nchunk * 256 + t;
    const int b = n >> 10, pos = n & 1023;
    const float* hb = h + b * 32768 + pos;
    float z[32];
    float zz = 0.f;
#pragma unroll
    for (int c = 0; c < 32; ++c) {
        z[c] = hb[c * 1024];
        zz += z[c] * z[c];
    }
    const int kbase = ks << 7;
    const float* cbb = cb + (kbase << 5);
    const float* ccb = ccp + kbase;
    float bd = 3.4e38f;
    int bk = 0;
#pragma unroll 1
    for (int kk = 0; kk < 128; kk += 2) {
        const float* r0 = cbb + (kk << 5);
        const float* r1 = r0 + 32;
        float d0a = 0.f, d0b = 0.f, d1a = 0.f, d1b = 0.f;
#pragma unroll
        for (int c = 0; c < 32; c += 2) {
            d0a += z[c] * r0[c];
            d0b += z[c + 1] * r0[c + 1];
            d1a += z[c] * r1[c];
            d1b += z[c + 1] * r1[c + 1];
        }
        const float dot0 = d0a + d0b;
        const float dot1 = d1a + d1b;
        const float e0 = (zz - 2.f * dot0) + ccb[kk];
        const float e1 = (zz - 2.f * dot1) + ccb[kk + 1];
        if (e0 < bd) { bd = e0; bk = kbase + kk; }
        if (e1 < bd) { bd = e1; bk = kbase + kk + 1; }
    }
    part[ks * 131072 + n] = make_float2(bd, (float)bk);
}

// ---------------------------------------------------------------------------
// K3b: combine 4 k-split partials per n (unchanged).
// ---------------------------------------------------------------------------
__global__ __launch_bounds__(256) void k_vq_comb(const float2* __restrict__ part,
                                                 float* __restrict__ idx_out,
                                                 float* __restrict__ partials) {
    const int t = threadIdx.x;
    const int n = blockIdx.x * 256 + t;
    float2 p0 = part[n];
    float2 p1 = part[131072 + n];
    float2 p2 = part[262144 + n];
    float2 p3 = part[393216 + n];
    float bd = p0.x;
    float bk = p0.y;
    if (p1.x < bd) { bd = p1.x; bk = p1.y; }
    if (p2.x < bd) { bd = p2.x; bk = p2.y; }
    if (p3.x < bd) { bd = p3.x; bk = p3.y; }
    idx_out[n] = bk;
    __shared__ float red[256];
    red[t] = bd;
    __syncthreads();
    for (int off = 128; off > 0; off >>= 1) {
        if (t < off) red[t] += red[t + off];
        __syncthreads();
    }
    if (t == 0) partials[blockIdx.x] = red[0];
}

// ---------------------------------------------------------------------------
// K4: conv3 (32->16, 3x3, SAME) on nearest-2x-upsampled h, + gelu.
// h[128,32,32,32] -> g[128,16,64,64]
// Odd row stride (35) + b32 reads: banks 3*rp+4*cg -> max 2-way (free).
// ---------------------------------------------------------------------------
__global__ __launch_bounds__(256) void k_conv3(const float* __restrict__ h,
                                               const float* __restrict__ w3,
                                               const float* __restrict__ b3,
                                               float* __restrict__ g) {
    __shared__ float hS[16 * 350];
    const int blk = blockIdx.x;
    const int b = blk >> 2, strip = blk & 3;
    const int i0 = strip * 8;
    const int t = threadIdx.x;
    const int co0 = __builtin_amdgcn_readfirstlane((t >> 6) << 2);
    const int lane = t & 63;
    const int rp = lane >> 3, cg = lane & 7;
    float acc[4][2][8];
#pragma unroll
    for (int cq = 0; cq < 4; cq++)
#pragma unroll
        for (int rr = 0; rr < 2; rr++)
#pragma unroll
            for (int u = 0; u < 8; u++) acc[cq][rr][u] = 0.f;
    const float* hb = h + b * 32768;
#pragma unroll 1
    for (int chunk = 0; chunk < 2; chunk++) {
        __syncthreads();
        for (int i = t; i < 16 * 340; i += 256) {
            const int cil = i / 340, rc = i % 340, r = rc / 34, c = rc % 34;
            const int gr = i0 - 1 + r, gc = c - 1;
            const float v = ((unsigned)gr < 32u && (unsigned)gc < 32u)
                ? hb[(chunk * 16 + cil) * 1024 + gr * 32 + gc] : 0.f;
            hS[cil * 350 + r * 35 + c] = v;
        }
        __syncthreads();
#pragma unroll 2
        for (int cil = 0; cil < 16; cil++) {
            const int ci = chunk * 16 + cil;
            float colr[3][6];
#pragma unroll
            for (int rr = 0; rr < 3; rr++) {
                const int rowb = cil * 350 + (rp + rr) * 35 + 4 * cg;
#pragma unroll
                for (int u = 0; u < 6; u++) colr[rr][u] = hS[rowb + u];
            }
#pragma unroll
            for (int cq = 0; cq < 4; cq++) {
                const float* wr = w3 + ((co0 + cq) * 32 + ci) * 9;
                float w[9];
#pragma unroll
                for (int k = 0; k < 9; k++) w[k] = wr[k];
                const float T00 = w[0], T01 = w[1], T02 = w[2];
                const float T10 = w[3] + w[6], T11 = w[4] + w[7], T12 = w[5] + w[8];
                const float T20 = w[0] + w[3], T21 = w[1] + w[4], T22 = w[2] + w[5];
                const float T30 = w[6], T31 = w[7], T32 = w[8];
                const float E01 = T01 + T02, O00 = T00 + T01;
                const float E11 = T11 + T12, O10 = T10 + T11;
                const float E21 = T21 + T22, O20 = T20 + T21;
                const float E31 = T31 + T32, O30 = T30 + T31;
#pragma unroll
                for (int mm = 0; mm < 4; mm++) {
                    acc[cq][0][2 * mm]     += T00 * colr[0][mm] + E01 * colr[0][mm + 1] + T10 * colr[1][mm] + E11 * colr[1][mm + 1];
                    acc[cq][0][2 * mm + 1] += O00 * colr[0][mm + 1] + T02 * colr[0][mm + 2] + O10 * colr[1][mm + 1] + T12 * colr[1][mm + 2];
                    acc[cq][1][2 * mm]     += T20 * colr[1][mm] + E21 * colr[1][mm + 1] + T30 * colr[2][mm] + E31 * colr[2][mm + 1];
                    acc[cq][1][2 * mm + 1] += O20 * colr[1][mm + 1] + T22 * colr[1][mm + 2] + O30 * colr[2][mm + 1] + T32 * colr[2][mm + 2];
                }
            }
        }
    }
    const int p_e = strip * 16 + 2 * rp;
#pragma unroll
    for (int cq = 0; cq < 4; cq++) {
        const float bias = b3[co0 + cq];
        float* gb = g + (b * 16 + co0 + cq) * 4096 + p_e * 64 + 8 * cg;
#pragma unroll
        for (int rr = 0; rr < 2; rr++) {
            float4 v0, v1;
            v0.x = gelu_f(acc[cq][rr][0] + bias);
            v0.y = gelu_f(acc[cq][rr][1] + bias);
            v0.z = gelu_f(acc[cq][rr][2] + bias);
            v0.w = gelu_f(acc[cq][rr][3] + bias);
            v1.x = gelu_f(acc[cq][rr][4] + bias);
            v1.y = gelu_f(acc[cq][rr][5] + bias);
            v1.z = gelu_f(acc[cq][rr][6] + bias);
            v1.w = gelu_f(acc[cq][rr][7] + bias);
            *(float4*)(gb + rr * 64) = v0;
            *(float4*)(gb + rr * 64 + 4) = v1;
        }
    }
}

// ---------------------------------------------------------------------------
// K5: conv4 (16->1, 3x3, SAME) on nearest-2x-upsampled g, + clip [-1,1].
// g[128,16,64,64] -> out[128,1,128,128]
// Odd row stride (69) + b32 reads: banks 5*rp+2*cg -> 2-way (free).
// ---------------------------------------------------------------------------
__global__ __launch_bounds__(256) void k_conv4(const float* __restrict__ g,
                                               const float* __restrict__ w4,
                                               const float* __restrict__ b4,
                                               float* __restrict__ out) {
    __shared__ float gS[8 * 690];
    const int blk = blockIdx.x;
    const int b = blk >> 3, strip = blk & 7;
    const int i0 = strip * 8;
    const int t = threadIdx.x;
    const int rp = t >> 5, cg = t & 31;
    float acc[2][4];
#pragma unroll
    for (int rr = 0; rr < 2; rr++)
#pragma unroll
        for (int u = 0; u < 4; u++) acc[rr][u] = 0.f;
    const float* gbs = g + b * 65536;
#pragma unroll 1
    for (int chunk = 0; chunk < 2; chunk++) {
        __syncthreads();
        for (int i = t; i < 8 * 660; i += 256) {
            const int cil = i / 660, rc = i % 660, r = rc / 66, c = rc % 66;
            const int gr = i0 - 1 + r, gc = c - 1;
            const float v = ((unsigned)gr < 64u && (unsigned)gc < 64u)
                ? gbs[(chunk * 8 + cil) * 4096 + gr * 64 + gc] : 0.f;
            gS[cil * 690 + r * 69 + c] = v;
        }
        __syncthreads();
#pragma unroll 2
        for (int cil = 0; cil < 8; cil++) {
            const int ci = chunk * 8 + cil;
            float colv[3][4];
#pragma unroll
            for (int rr = 0; rr < 3; rr++) {
                const int rowb = cil * 690 + (rp + rr) * 69 + 2 * cg;
#pragma unroll
                for (int u = 0; u < 4; u++) colv[rr][u] = gS[rowb + u];
            }
            const float* wr = w4 + ci * 9;
            float w[9];
#pragma unroll
            for (int k = 0; k < 9; k++) w[k] = wr[k];
            const float T00 = w[0], T01 = w[1], T02 = w[2];
            const float T10 = w[3] + w[6], T11 = w[4] + w[7], T12 = w[5] + w[8];
            const float T20 = w[0] + w[3], T21 = w[1] + w[4], T22 = w[2] + w[5];
            const float T30 = w[6], T31 = w[7], T32 = w[8];
            const float E01 = T01 + T02, O00 = T00 + T01;
            const float E11 = T11 + T12, O10 = T10 + T11;
            const float E21 = T21 + T22, O20 = T20 + T21;
            const float E31 = T31 + T32, O30 = T30 + T31;
#pragma unroll
            for (int mm = 0; mm < 2; mm++) {
                acc[0][2 * mm]     += T00 * colv[0][mm] + E01 * colv[0][mm + 1] + T10 * colv[1][mm] + E11 * colv[1][mm + 1];
                acc[0][2 * mm + 1] += O00 * colv[0][mm + 1] + T02 * colv[0][mm + 2] + O10 * colv[1][mm + 1] + T12 * colv[1][mm + 2];
                acc[1][2 * mm]     += T20 * colv[1][mm] + E21 * colv[1][mm + 1] + T30 * colv[2][mm] + E31 * colv[2][mm + 1];
                acc[1][2 * mm + 1] += O20 * colv[1][mm + 1] + T22 * colv[1][mm + 2] + O30 * colv[2][mm + 1] + T32 * colv[2][mm + 2];
            }
        }
    }
    const float bias = b4[0];
    const int p_e = strip * 16 + 2 * rp;
    float* ob = out + b * 16384 + p_e * 128 + 4 * cg;
#pragma unroll
    for (int rr = 0; rr < 2; rr++) {
        float4 v;
        v.x = fminf(fmaxf(acc[rr][0] + bias, -1.f), 1.f);
        v.y = fminf(fmaxf(acc[rr][1] + bias, -1.f), 1.f);
        v.z = fminf(fmaxf(acc[rr][2] + bias, -1.f), 1.f);
        v.w = fminf(fmaxf(acc[rr][3] + bias, -1.f), 1.f);
        *(float4*)(ob + rr * 128) = v;
    }
}

// ---------------------------------------------------------------------------
// K6: deterministic loss reduction
// ---------------------------------------------------------------------------
__global__ __launch_bounds__(256) void k_reduce(const float* __restrict__ partials,
                                                float* __restrict__ loss) {
    __shared__ float red[256];
    const int t = threadIdx.x;
    float s = 0.f;
    for (int i = t; i < 512; i += 256) s += partials[i];
    red[t] = s;
    __syncthreads();
    for (int off = 128; off > 0; off >>= 1) {
        if (t < off) red[t] += red[t + off];
        __syncthreads();
    }
    if (t == 0) loss[0] = red[0] * (1.0f / 4194304.0f);
}

extern "C" void kernel_launch(void* const* d_in, const int* in_sizes, int n_in,
                              void* d_out, int out_size, void* d_ws, size_t ws_size,
                              hipStream_t stream) {
    const float* x  = (const float*)d_in[0];
    const float* w1 = (const float*)d_in[1];
    const float* b1 = (const float*)d_in[2];
    const float* w2 = (const float*)d_in[3];
    const float* b2 = (const float*)d_in[4];
    const float* cb = (const float*)d_in[5];
    const float* w3 = (const float*)d_in[6];
    const float* b3 = (const float*)d_in[7];
    const float* w4 = (const float*)d_in[8];
    const float* b4 = (const float*)d_in[9];

    float* ws = (float*)d_ws;
    float* h1 = ws;                  // 8388608 floats [128,16,64,64]
    float* h  = ws + 8388608;        // 4194304 floats [128,32,32,32]
    float* g  = h1;                  // alias: h1 dead after k_conv2
    float2* part = (float2*)ws;      // alias h1: live only vq_part -> vq_comb
    float* ccp = ws + 12582912;      // 512 floats
    float* pa  = ws + 12583424;      // 512 floats
    float* outp = (float*)d_out;     // [out 2097152][idx 131072][loss 1]

    k_prep<<<2, 256, 0, stream>>>(cb, ccp);
    k_conv1<<<2048, 256, 0, stream>>>(x, w1, b1, h1);
    k_conv2<<<2048, 256, 0, stream>>>(h1, w2, b2, h);
    k_vq_part<<<2048, 256, 0, stream>>>(h, cb, ccp, part);
    k_vq_comb<<<512, 256, 0, stream>>>(part, outp + 2097152, pa);
    k_conv3<<<512, 256, 0, stream>>>(h, w3, b3, g);
    k_conv4<<<1024, 256, 0, stream>>>(g, w4, b4, outp);
    k_reduce<<<1, 256, 0, stream>>>(pa, outp + 2228224);
}

// Round 6
// 238.950 us; speedup vs baseline: 1.0169x; 1.0169x over previous
//
#include <hip/hip_runtime.h>
#include <math.h>

typedef float f32x2 __attribute__((ext_vector_type(2)));

__device__ __forceinline__ float gelu_f(float x) {
    return 0.5f * x * (1.0f + erff(x * 0.7071067811865476f));
}

// ---------------------------------------------------------------------------
// K0: prep: cc[k] = ||cb_k||^2 ; transformed upsample-conv weights for
// conv3 (w3t[co][ci][16]) and conv4 (w4t[ci][16]).
// Order: {T00,O00,E01,T02, T10,O10,E11,T12, T20,O20,E21,T22, T30,O30,E31,T32}
// ---------------------------------------------------------------------------
__global__ __launch_bounds__(256) void k_prep(const float* __restrict__ cb,
                                              const float* __restrict__ w3,
                                              const float* __restrict__ w4,
                                              float* __restrict__ ccp,
                                              float* __restrict__ w3t,
                                              float* __restrict__ w4t) {
    const int id = blockIdx.x * 256 + threadIdx.x;   // 0..511
    {
        const float* row = cb + id * 32;
        float s = 0.f;
#pragma unroll
        for (int c = 0; c < 32; ++c) s += row[c] * row[c];
        ccp[id] = s;
    }
    {
        const float* w = w3 + id * 9;   // id = co*32+ci
        const float T00 = w[0], T01 = w[1], T02 = w[2];
        const float T10 = w[3] + w[6], T11 = w[4] + w[7], T12 = w[5] + w[8];
        const float T20 = w[0] + w[3], T21 = w[1] + w[4], T22 = w[2] + w[5];
        const float T30 = w[6], T31 = w[7], T32 = w[8];
        float* o = w3t + id * 16;
        o[0] = T00; o[1] = T00 + T01; o[2] = T01 + T02; o[3] = T02;
        o[4] = T10; o[5] = T10 + T11; o[6] = T11 + T12; o[7] = T12;
        o[8] = T20; o[9] = T20 + T21; o[10] = T21 + T22; o[11] = T22;
        o[12] = T30; o[13] = T30 + T31; o[14] = T31 + T32; o[15] = T32;
    }
    if (id < 16) {
        const float* w = w4 + id * 9;
        const float T00 = w[0], T01 = w[1], T02 = w[2];
        const float T10 = w[3] + w[6], T11 = w[4] + w[7], T12 = w[5] + w[8];
        const float T20 = w[0] + w[3], T21 = w[1] + w[4], T22 = w[2] + w[5];
        const float T30 = w[6], T31 = w[7], T32 = w[8];
        float* o = w4t + id * 16;
        o[0] = T00; o[1] = T00 + T01; o[2] = T01 + T02; o[3] = T02;
        o[4] = T10; o[5] = T10 + T11; o[6] = T11 + T12; o[7] = T12;
        o[8] = T20; o[9] = T20 + T21; o[10] = T21 + T22; o[11] = T22;
        o[12] = T30; o[13] = T30 + T31; o[14] = T31 + T32; o[15] = T32;
    }
}

// ---------------------------------------------------------------------------
// K1: conv1 (1->16, 3x3, SAME) + maxpool2 + gelu (unchanged from R5)
// ---------------------------------------------------------------------------
__global__ __launch_bounds__(256) void k_conv1(const float* __restrict__ x,
                                               const float* __restrict__ w1,
                                               const float* __restrict__ b1,
                                               float* __restrict__ h1) {
    __shared__ float xs[34 * 38];
    const int blk = blockIdx.x;
    const int b = blk >> 4;
    const int tile = blk & 15;
    const int ti = (tile >> 2) << 4, tj = (tile & 3) << 4;
    const int t = threadIdx.x;
    const float* xb = x + b * 16384;
    for (int i = t; i < 34 * 34; i += 256) {
        const int r = i / 34, c = i % 34;
        const int gr = 2 * ti - 1 + r, gc = 2 * tj - 1 + c;
        const float v = ((unsigned)gr < 128u && (unsigned)gc < 128u) ? xb[gr * 128 + gc] : 0.f;
        xs[r * 38 + (c & 1) * 19 + (c >> 1)] = v;
    }
    __syncthreads();
    const int jj = t & 15, ii = t >> 4;
    float pat[4][4];
#pragma unroll
    for (int r = 0; r < 4; r++) {
        const int row = (2 * ii + r) * 38;
        pat[r][0] = xs[row + jj];
        pat[r][1] = xs[row + 19 + jj];
        pat[r][2] = xs[row + jj + 1];
        pat[r][3] = xs[row + 20 + jj];
    }
    const int obase = b * 65536 + (ti + ii) * 64 + (tj + jj);
#pragma unroll 2
    for (int co = 0; co < 16; co++) {
        const float* wr = w1 + co * 9;
        float w[9];
#pragma unroll
        for (int k = 0; k < 9; k++) w[k] = wr[k];
        float s00 = 0.f, s01 = 0.f, s10 = 0.f, s11 = 0.f;
#pragma unroll
        for (int ty = 0; ty < 3; ty++)
#pragma unroll
            for (int tx = 0; tx < 3; tx++) {
                const float wv = w[ty * 3 + tx];
                s00 += wv * pat[ty][tx];
                s01 += wv * pat[ty][tx + 1];
                s10 += wv * pat[ty + 1][tx];
                s11 += wv * pat[ty + 1][tx + 1];
            }
        const float m = fmaxf(fmaxf(s00, s01), fmaxf(s10, s11)) + b1[co];
        h1[obase + co * 4096] = gelu_f(m);
    }
}

// ---------------------------------------------------------------------------
// K2: conv2 (16->32, 3x3, SAME) + maxpool2 — f32x2 packed (v_pk_fma_f32).
// A[q] = {acc0,acc1}, B[q] = {acc2,acc3}; each half keeps the exact prior
// FMA chain order -> bit-identical h.
// ---------------------------------------------------------------------------
__global__ __launch_bounds__(256) void k_conv2(const float* __restrict__ h1,
                                               const float* __restrict__ w2,
                                               const float* __restrict__ b2,
                                               float* __restrict__ h) {
    __shared__ float hs[16 * 360];
    const int blk = blockIdx.x;
    const int b = blk >> 4;
    const int tile = blk & 15;
    const int ti = (tile >> 2) << 3, tj = (tile & 3) << 3;
    const int t = threadIdx.x;
    const float* h1b = h1 + b * 65536;
    for (int i = t; i < 16 * 324; i += 256) {
        const int ci = i / 324, rc = i % 324, r = rc / 18, c = rc % 18;
        const int gr = 2 * ti - 1 + r, gc = 2 * tj - 1 + c;
        const float v = ((unsigned)gr < 64u && (unsigned)gc < 64u) ? h1b[ci * 4096 + gr * 64 + gc] : 0.f;
        hs[ci * 360 + r * 20 + (c & 1) * 10 + (c >> 1)] = v;
    }
    __syncthreads();
    const int co0 = __builtin_amdgcn_readfirstlane((t >> 6) << 3);
    const int lane = t & 63;
    const int irow = lane >> 3, j = lane & 7;
    f32x2 A[8], B[8];
#pragma unroll
    for (int q = 0; q < 8; q++) { A[q] = (f32x2){0.f, 0.f}; B[q] = (f32x2){0.f, 0.f}; }
    const float* wbase = w2 + co0 * 144;
#pragma unroll 4
    for (int ci = 0; ci < 16; ci++) {
        f32x2 P[4][3];
#pragma unroll
        for (int r = 0; r < 4; r++) {
            const int row = ci * 360 + (2 * irow + r) * 20;
            const float e0 = hs[row + j];
            const float o0 = hs[row + 10 + j];
            const float e1 = hs[row + j + 1];
            const float o1 = hs[row + 11 + j];
            P[r][0] = (f32x2){e0, o0};
            P[r][1] = (f32x2){o0, e1};
            P[r][2] = (f32x2){e1, o1};
        }
#pragma unroll
        for (int q = 0; q < 8; q++) {
            const float* wr = wbase + q * 144 + ci * 9;
            float w[9];
#pragma unroll
            for (int k = 0; k < 9; k++) w[k] = wr[k];
#pragma unroll
            for (int ty = 0; ty < 3; ty++)
#pragma unroll
                for (int tx = 0; tx < 3; tx++) {
                    const float wv = w[ty * 3 + tx];
                    A[q] += P[ty][tx] * wv;
                    B[q] += P[ty + 1][tx] * wv;
                }
        }
    }
    float* hb = h + (b * 32 + co0) * 1024 + (ti + irow) * 32 + tj + j;
#pragma unroll
    for (int q = 0; q < 8; q++) {
        hb[q * 1024] = fmaxf(fmaxf(A[q].x, A[q].y), fmaxf(B[q].x, B[q].y)) + b2[co0 + q];
    }
}

// ---------------------------------------------------------------------------
// K3a: VQ partial argmin — f32x2 packed dot. D0.x/.y reproduce the prior
// d0a/d0b chains exactly; zz kept as the original scalar chain.
// ---------------------------------------------------------------------------
__global__ __launch_bounds__(256) void k_vq_part(const float* __restrict__ h,
                                                 const float* __restrict__ cb,
                                                 const float* __restrict__ ccp,
                                                 float2* __restrict__ part) {
    const int blk = blockIdx.x;
    const int nchunk = blk >> 2, ks = blk & 3;
    const int t = threadIdx.x;
    const int n = nchunk * 256 + t;
    const int b = n >> 10, pos = n & 1023;
    const float* hb = h + b * 32768 + pos;
    float z[32];
    float zz = 0.f;
#pragma unroll
    for (int c = 0; c < 32; ++c) {
        z[c] = hb[c * 1024];
        zz += z[c] * z[c];
    }
    f32x2 z2[16];
#pragma unroll
    for (int i = 0; i < 16; ++i) z2[i] = (f32x2){z[2 * i], z[2 * i + 1]};
    const int kbase = ks << 7;
    const float* cbb = cb + (kbase << 5);
    const float* ccb = ccp + kbase;
    float bd = 3.4e38f;
    int bk = 0;
#pragma unroll 1
    for (int kk = 0; kk < 128; kk += 2) {
        const f32x2* r0 = (const f32x2*)(cbb + (kk << 5));
        const f32x2* r1 = (const f32x2*)(cbb + (kk << 5) + 32);
        f32x2 D0 = (f32x2){0.f, 0.f};
        f32x2 D1 = (f32x2){0.f, 0.f};
#pragma unroll
        for (int i = 0; i < 16; ++i) {
            D0 += z2[i] * r0[i];
            D1 += z2[i] * r1[i];
        }
        const float dot0 = D0.x + D0.y;
        const float dot1 = D1.x + D1.y;
        const float e0 = (zz - 2.f * dot0) + ccb[kk];
        const float e1 = (zz - 2.f * dot1) + ccb[kk + 1];
        if (e0 < bd) { bd = e0; bk = kbase + kk; }
        if (e1 < bd) { bd = e1; bk = kbase + kk + 1; }
    }
    part[ks * 131072 + n] = make_float2(bd, (float)bk);
}

// ---------------------------------------------------------------------------
// K3b: combine 4 k-split partials per n (unchanged).
// ---------------------------------------------------------------------------
__global__ __launch_bounds__(256) void k_vq_comb(const float2* __restrict__ part,
                                                 float* __restrict__ idx_out,
                                                 float* __restrict__ partials) {
    const int t = threadIdx.x;
    const int n = blockIdx.x * 256 + t;
    float2 p0 = part[n];
    float2 p1 = part[131072 + n];
    float2 p2 = part[262144 + n];
    float2 p3 = part[393216 + n];
    float bd = p0.x;
    float bk = p0.y;
    if (p1.x < bd) { bd = p1.x; bk = p1.y; }
    if (p2.x < bd) { bd = p2.x; bk = p2.y; }
    if (p3.x < bd) { bd = p3.x; bk = p3.y; }
    idx_out[n] = bk;
    __shared__ float red[256];
    red[t] = bd;
    __syncthreads();
    for (int off = 128; off > 0; off >>= 1) {
        if (t < off) red[t] += red[t + off];
        __syncthreads();
    }
    if (t == 0) partials[blockIdx.x] = red[0];
}

// ---------------------------------------------------------------------------
// K4: conv3 — weight combines hoisted to k_prep (w3t); FMA expressions and
// order identical to R5 -> bit-identical g.
// ---------------------------------------------------------------------------
__global__ __launch_bounds__(256) void k_conv3(const float* __restrict__ h,
                                               const float* __restrict__ w3t,
                                               const float* __restrict__ b3,
                                               float* __restrict__ g) {
    __shared__ float hS[16 * 350];
    const int blk = blockIdx.x;
    const int b = blk >> 2, strip = blk & 3;
    const int i0 = strip * 8;
    const int t = threadIdx.x;
    const int co0 = __builtin_amdgcn_readfirstlane((t >> 6) << 2);
    const int lane = t & 63;
    const int rp = lane >> 3, cg = lane & 7;
    float acc[4][2][8];
#pragma unroll
    for (int cq = 0; cq < 4; cq++)
#pragma unroll
        for (int rr = 0; rr < 2; rr++)
#pragma unroll
            for (int u = 0; u < 8; u++) acc[cq][rr][u] = 0.f;
    const float* hb = h + b * 32768;
#pragma unroll 1
    for (int chunk = 0; chunk < 2; chunk++) {
        __syncthreads();
        for (int i = t; i < 16 * 340; i += 256) {
            const int cil = i / 340, rc = i % 340, r = rc / 34, c = rc % 34;
            const int gr = i0 - 1 + r, gc = c - 1;
            const float v = ((unsigned)gr < 32u && (unsigned)gc < 32u)
                ? hb[(chunk * 16 + cil) * 1024 + gr * 32 + gc] : 0.f;
            hS[cil * 350 + r * 35 + c] = v;
        }
        __syncthreads();
#pragma unroll 2
        for (int cil = 0; cil < 16; cil++) {
            const int ci = chunk * 16 + cil;
            float colr[3][6];
#pragma unroll
            for (int rr = 0; rr < 3; rr++) {
                const int rowb = cil * 350 + (rp + rr) * 35 + 4 * cg;
#pragma unroll
                for (int u = 0; u < 6; u++) colr[rr][u] = hS[rowb + u];
            }
#pragma unroll
            for (int cq = 0; cq < 4; cq++) {
                const float* wt = w3t + ((co0 + cq) * 32 + ci) * 16;
                const float T00 = wt[0], O00 = wt[1], E01 = wt[2], T02 = wt[3];
                const float T10 = wt[4], O10 = wt[5], E11 = wt[6], T12 = wt[7];
                const float T20 = wt[8], O20 = wt[9], E21 = wt[10], T22 = wt[11];
                const float T30 = wt[12], O30 = wt[13], E31 = wt[14], T32 = wt[15];
#pragma unroll
                for (int mm = 0; mm < 4; mm++) {
                    acc[cq][0][2 * mm]     += T00 * colr[0][mm] + E01 * colr[0][mm + 1] + T10 * colr[1][mm] + E11 * colr[1][mm + 1];
                    acc[cq][0][2 * mm + 1] += O00 * colr[0][mm + 1] + T02 * colr[0][mm + 2] + O10 * colr[1][mm + 1] + T12 * colr[1][mm + 2];
                    acc[cq][1][2 * mm]     += T20 * colr[1][mm] + E21 * colr[1][mm + 1] + T30 * colr[2][mm] + E31 * colr[2][mm + 1];
                    acc[cq][1][2 * mm + 1] += O20 * colr[1][mm + 1] + T22 * colr[1][mm + 2] + O30 * colr[2][mm + 1] + T32 * colr[2][mm + 2];
                }
            }
        }
    }
    const int p_e = strip * 16 + 2 * rp;
#pragma unroll
    for (int cq = 0; cq < 4; cq++) {
        const float bias = b3[co0 + cq];
        float* gb = g + (b * 16 + co0 + cq) * 4096 + p_e * 64 + 8 * cg;
#pragma unroll
        for (int rr = 0; rr < 2; rr++) {
            float4 v0, v1;
            v0.x = gelu_f(acc[cq][rr][0] + bias);
            v0.y = gelu_f(acc[cq][rr][1] + bias);
            v0.z = gelu_f(acc[cq][rr][2] + bias);
            v0.w = gelu_f(acc[cq][rr][3] + bias);
            v1.x = gelu_f(acc[cq][rr][4] + bias);
            v1.y = gelu_f(acc[cq][rr][5] + bias);
            v1.z = gelu_f(acc[cq][rr][6] + bias);
            v1.w = gelu_f(acc[cq][rr][7] + bias);
            *(float4*)(gb + rr * 64) = v0;
            *(float4*)(gb + rr * 64 + 4) = v1;
        }
    }
}

// ---------------------------------------------------------------------------
// K5: conv4 — weight combines from w4t; otherwise identical to R5.
// ---------------------------------------------------------------------------
__global__ __launch_bounds__(256) void k_conv4(const float* __restrict__ g,
                                               const float* __restrict__ w4t,
                                               const float* __restrict__ b4,
                                               float* __restrict__ out) {
    __shared__ float gS[8 * 690];
    const int blk = blockIdx.x;
    const int b = blk >> 3, strip = blk & 7;
    const int i0 = strip * 8;
    const int t = threadIdx.x;
    const int rp = t >> 5, cg = t & 31;
    float acc[2][4];
#pragma unroll
    for (int rr = 0; rr < 2; rr++)
#pragma unroll
        for (int u = 0; u < 4; u++) acc[rr][u] = 0.f;
    const float* gbs = g + b * 65536;
#pragma unroll 1
    for (int chunk = 0; chunk < 2; chunk++) {
        __syncthreads();
        for (int i = t; i < 8 * 660; i += 256) {
            const int cil = i / 660, rc = i % 660, r = rc / 66, c = rc % 66;
            const int gr = i0 - 1 + r, gc = c - 1;
            const float v = ((unsigned)gr < 64u && (unsigned)gc < 64u)
                ? gbs[(chunk * 8 + cil) * 4096 + gr * 64 + gc] : 0.f;
            gS[cil * 690 + r * 69 + c] = v;
        }
        __syncthreads();
#pragma unroll 2
        for (int cil = 0; cil < 8; cil++) {
            const int ci = chunk * 8 + cil;
            float colv[3][4];
#pragma unroll
            for (int rr = 0; rr < 3; rr++) {
                const int rowb = cil * 690 + (rp + rr) * 69 + 2 * cg;
#pragma unroll
                for (int u = 0; u < 4; u++) colv[rr][u] = gS[rowb + u];
            }
            const float* wt = w4t + ci * 16;
            const float T00 = wt[0], O00 = wt[1], E01 = wt[2], T02 = wt[3];
            const float T10 = wt[4], O10 = wt[5], E11 = wt[6], T12 = wt[7];
            const float T20 = wt[8], O20 = wt[9], E21 = wt[10], T22 = wt[11];
            const float T30 = wt[12], O30 = wt[13], E31 = wt[14], T32 = wt[15];
#pragma unroll
            for (int mm = 0; mm < 2; mm++) {
                acc[0][2 * mm]     += T00 * colv[0][mm] + E01 * colv[0][mm + 1] + T10 * colv[1][mm] + E11 * colv[1][mm + 1];
                acc[0][2 * mm + 1] += O00 * colv[0][mm + 1] + T02 * colv[0][mm + 2] + O10 * colv[1][mm + 1] + T12 * colv[1][mm + 2];
                acc[1][2 * mm]     += T20 * colv[1][mm] + E21 * colv[1][mm + 1] + T30 * colv[2][mm] + E31 * colv[2][mm + 1];
                acc[1][2 * mm + 1] += O20 * colv[1][mm + 1] + T22 * colv[1][mm + 2] + O30 * colv[2][mm + 1] + T32 * colv[2][mm + 2];
            }
        }
    }
    const float bias = b4[0];
    const int p_e = strip * 16 + 2 * rp;
    float* ob = out + b * 16384 + p_e * 128 + 4 * cg;
#pragma unroll
    for (int rr = 0; rr < 2; rr++) {
        float4 v;
        v.x = fminf(fmaxf(acc[rr][0] + bias, -1.f), 1.f);
        v.y = fminf(fmaxf(acc[rr][1] + bias, -1.f), 1.f);
        v.z = fminf(fmaxf(acc[rr][2] + bias, -1.f), 1.f);
        v.w = fminf(fmaxf(acc[rr][3] + bias, -1.f), 1.f);
        *(float4*)(ob + rr * 128) = v;
    }
}

// ---------------------------------------------------------------------------
// K6: deterministic loss reduction
// ---------------------------------------------------------------------------
__global__ __launch_bounds__(256) void k_reduce(const float* __restrict__ partials,
                                                float* __restrict__ loss) {
    __shared__ float red[256];
    const int t = threadIdx.x;
    float s = 0.f;
    for (int i = t; i < 512; i += 256) s += partials[i];
    red[t] = s;
    __syncthreads();
    for (int off = 128; off > 0; off >>= 1) {
        if (t < off) red[t] += red[t + off];
        __syncthreads();
    }
    if (t == 0) loss[0] = red[0] * (1.0f / 4194304.0f);
}

extern "C" void kernel_launch(void* const* d_in, const int* in_sizes, int n_in,
                              void* d_out, int out_size, void* d_ws, size_t ws_size,
                              hipStream_t stream) {
    const float* x  = (const float*)d_in[0];
    const float* w1 = (const float*)d_in[1];
    const float* b1 = (const float*)d_in[2];
    const float* w2 = (const float*)d_in[3];
    const float* b2 = (const float*)d_in[4];
    const float* cb = (const float*)d_in[5];
    const float* w3 = (const float*)d_in[6];
    const float* b3 = (const float*)d_in[7];
    const float* w4 = (const float*)d_in[8];
    const float* b4 = (const float*)d_in[9];

    float* ws = (float*)d_ws;
    float* h1 = ws;                  // 8388608 floats [128,16,64,64]
    float* h  = ws + 8388608;        // 4194304 floats [128,32,32,32]
    float* g  = h1;                  // alias: h1 dead after k_conv2
    float2* part = (float2*)ws;      // alias h1: live only vq_part -> vq_comb
    float* ccp = ws + 12582912;      // 512 floats
    float* pa  = ws + 12583424;      // 512 floats
    float* w3t = ws + 12583936;      // 8192 floats (16co x 32ci x 16)
    float* w4t = ws + 12592128;      // 256 floats (16ci x 16)
    float* outp = (float*)d_out;     // [out 2097152][idx 131072][loss 1]

    k_prep<<<2, 256, 0, stream>>>(cb, w3, w4, ccp, w3t, w4t);
    k_conv1<<<2048, 256, 0, stream>>>(x, w1, b1, h1);
    k_conv2<<<2048, 256, 0, stream>>>(h1, w2, b2, h);
    k_vq_part<<<2048, 256, 0, stream>>>(h, cb, ccp, part);
    k_vq_comb<<<512, 256, 0, stream>>>(part, outp + 2097152, pa);
    k_conv3<<<512, 256, 0, stream>>>(h, w3t, b3, g);
    k_conv4<<<1024, 256, 0, stream>>>(g, w4t, b4, outp);
    k_reduce<<<1, 256, 0, stream>>>(pa, outp + 2228224);
}